// Round 15
// baseline (3908.617 us; speedup 1.0000x reference)
//
#include <hip/hip_runtime.h>
#include <cstddef>

#define T_STEPS 1024
#define NB      64
#define DIN     128
#define HID     256
#define WPG     16

typedef unsigned short u16;
typedef unsigned int   u32;
typedef unsigned long long u64;
typedef __attribute__((ext_vector_type(8))) short short8;
typedef __attribute__((ext_vector_type(4))) float f32x4;

// ws byte offsets
#define WG_OFF   0u          // bf16 weights [2][1024 rows j*4+q][384 k] = 1,572,864 B
#define BIAS_OFF 1572864u    // f32 [2][1024]
#define XB_OFF   1581056u    // bf16 x [1024][64][128] = 16,777,216 B
#define HB_OFF   18358272u   // u16 hbuf [2 par][8 grp][16 b][256 j] = 131,072 B
#define FL_OFF   18489344u   // u32 flags [8 grp][16 wg] = 512 B

#define OUT_MAIN (T_STEPS * NB * 2 * HID)
#define TAIL_H   OUT_MAIN
#define TAIL_C   (OUT_MAIN + 2 * NB * HID)

__device__ __forceinline__ u16 f2bf(float f) {
  unsigned u = __float_as_uint(f);
  return (u16)((u + 0x7fffu + ((u >> 16) & 1u)) >> 16);  // RNE
}
__device__ __forceinline__ float sigm(float v) { return 1.f / (1.f + __expf(-v)); }
__device__ __forceinline__ float tanh_fast(float x) {
  float e = __expf(-2.f * fabsf(x));
  float r = (1.f - e) / (1.f + e);
  return x < 0.f ? -r : r;
}

__global__ void prep_kernel(const float* __restrict__ x,
                            const float* __restrict__ Wih_f, const float* __restrict__ Whh_f,
                            const float* __restrict__ bih_f, const float* __restrict__ bhh_f,
                            const float* __restrict__ Wih_r, const float* __restrict__ Whh_r,
                            const float* __restrict__ bih_r, const float* __restrict__ bhh_r,
                            const float* __restrict__ hx,
                            u16* __restrict__ Wg, float* __restrict__ bias4,
                            u16* __restrict__ xb, u16* __restrict__ hbuf,
                            u32* __restrict__ flags) {
  // segments: W 786432 | bias 2048 | xb 8388608 | hx-cells 32768 | flags 128
  const int total = 786432 + 2048 + 8388608 + 32768 + 128;
  for (int i = blockIdx.x * blockDim.x + threadIdx.x; i < total;
       i += gridDim.x * blockDim.x) {
    if (i < 786432) {
      int d = i / 393216;
      int r = i - d * 393216;
      int rowg = r / 384, k = r - rowg * 384;   // rowg = j*4+q interleaved
      int j = rowg >> 2, q = rowg & 3;
      int g = q * HID + j;                      // torch gate row
      const float* Wih = d ? Wih_r : Wih_f;
      const float* Whh = d ? Whh_r : Whh_f;
      float v = (k < DIN) ? Wih[g * DIN + k] : Whh[g * HID + (k - DIN)];
      Wg[i] = f2bf(v);
    } else if (i < 786432 + 2048) {
      int r = i - 786432;
      int d = r >> 10, rowg = r & 1023;
      int j = rowg >> 2, q = rowg & 3;
      int g = q * HID + j;
      bias4[r] = d ? (bih_r[g] + bhh_r[g]) : (bih_f[g] + bhh_f[g]);
    } else if (i < 786432 + 2048 + 8388608) {
      int r = i - (786432 + 2048);
      xb[r] = f2bf(x[r]);                       // [t][b][k]
    } else if (i < 786432 + 2048 + 8388608 + 32768) {
      int r = i - (786432 + 2048 + 8388608);    // (d*64+b)*256 + j
      int d = r >> 14, b = (r >> 8) & 63, j = r & 255;
      int grp = d * 4 + (b >> 4), bb = b & 15;
      hbuf[((size_t)(8 + grp) * 16 + bb) * 256 + j] = f2bf(hx[r]);  // parity 1
      hbuf[((size_t)(0 + grp) * 16 + bb) * 256 + j] = 0;            // parity 0
    } else {
      flags[i - (786432 + 2048 + 8388608 + 32768)] = 0u;
    }
  }
}

#define MFMA __builtin_amdgcn_mfma_f32_16x16x32_bf16
#define ALD64(P) __hip_atomic_load((P), __ATOMIC_RELAXED, __HIP_MEMORY_SCOPE_AGENT)
#define MN2(F) { u32 a_ = (u32)(F), b_ = (u32)((F) >> 32); \
                 mn = mn < a_ ? mn : a_; mn = mn < b_ ? mn : b_; }
#define MKA(LO, HI) ({ uint4 u_; u_.x = (u32)(LO); u_.y = (u32)((LO) >> 32); \
                       u_.z = (u32)(HI); u_.w = (u32)((HI) >> 32); \
                       *(short8*)&u_; })
// issue the 16 agent loads that form this lane's h A-fragments (parity PAR)
#define LOADH(PAR) { \
    const u64* hp_ = (const u64*)(hbuf + ((size_t)((PAR) * 8 + grp) * 16 + (l & 15)) * 256 \
                                  + ((l >> 4) * 8)); \
    hA0 = ALD64(hp_ + 0);  hB0 = ALD64(hp_ + 1); \
    hA1 = ALD64(hp_ + 8);  hB1 = ALD64(hp_ + 9); \
    hA2 = ALD64(hp_ + 16); hB2 = ALD64(hp_ + 17); \
    hA3 = ALD64(hp_ + 24); hB3 = ALD64(hp_ + 25); \
    hA4 = ALD64(hp_ + 32); hB4 = ALD64(hp_ + 33); \
    hA5 = ALD64(hp_ + 40); hB5 = ALD64(hp_ + 41); \
    hA6 = ALD64(hp_ + 48); hB6 = ALD64(hp_ + 49); \
    hA7 = ALD64(hp_ + 56); hB7 = ALD64(hp_ + 57); }

// 128 WGs x 256 thr. grp = bid&7 = d*4+btile (16 WGs/group), jsl = bid>>3.
// Per WG: 64 gate rows, 16 batches. Weights in 12 named VGPR fragments (r13-
// proven, no spill). h travels LLC -> A-fragment VGPRs directly (no LDS park,
// no B1): 16 u64 agent loads per lane in exact MFMA A-layout, streaming into
// the MFMA chain. Exchange ordering = r9 (drain -> B3 -> flag -> poll -> B4)
// with per-producer value flags (no RMW).
__global__ __launch_bounds__(256, 1) void lstm_r15(
    const u16* __restrict__ Wg, const float* __restrict__ bias4,
    const u16* __restrict__ xb, const float* __restrict__ cx,
    u16* __restrict__ hbuf, u32* __restrict__ flags,
    float* __restrict__ out) {
  extern __shared__ char smem[];
  u16* xsh  = (u16*)smem;                 // [2][16][136]  8,704 B
  float* gl = (float*)(smem + 8704);      // [16 m][68 n]  4,352 B (tot 13,056)

  const int tid = threadIdx.x;
  const int bid = blockIdx.x;
  const int grp = bid & 7;
  const int jsl = bid >> 3;
  const int d = grp >> 2, b0 = (grp & 3) * 16;
  const int w = tid >> 6, l = tid & 63;

  // one-time: 12 weight fragments -> named VGPRs (16-B aligned global loads)
  const u16* wgb = Wg + ((size_t)(d * 1024 + jsl * 64 + w * 16 + (l & 15))) * 384
                      + (l >> 4) * 8;
  short8 Wx0 = *(const short8*)(wgb + 0);
  short8 Wx1 = *(const short8*)(wgb + 32);
  short8 Wx2 = *(const short8*)(wgb + 64);
  short8 Wx3 = *(const short8*)(wgb + 96);
  short8 Wh0 = *(const short8*)(wgb + 128);
  short8 Wh1 = *(const short8*)(wgb + 160);
  short8 Wh2 = *(const short8*)(wgb + 192);
  short8 Wh3 = *(const short8*)(wgb + 224);
  short8 Wh4 = *(const short8*)(wgb + 256);
  short8 Wh5 = *(const short8*)(wgb + 288);
  short8 Wh6 = *(const short8*)(wgb + 320);
  short8 Wh7 = *(const short8*)(wgb + 352);
  const float bv = bias4[d * 1024 + jsl * 64 + w * 16 + (l & 15)];

  // elementwise identity (r9 coalesced): eb = batch, ej = j slot
  const int eb = tid >> 4, ej = tid & 15;
  const int jglob = jsl * 16 + ej;
  float c_reg = cx[((size_t)d * NB + b0 + eb) * HID + jglob];

  const int xr_row = tid >> 4;            // x stage row (16 batches)
  const int xc = (tid & 15) * 8;          // 8 u16 = 16 B per thread

  // prologue: stage x(t0), prefetch x(t1), issue h(init) A-frag loads (parity 1)
  { int t0 = d ? 1023 : 0;
    *(uint4*)&xsh[(0 * 16 + xr_row) * 136 + xc] =
        *(const uint4*)&xb[((size_t)t0 * NB + b0 + xr_row) * DIN + xc]; }
  uint4 xv;
  { int t1 = d ? 1022 : 1;
    xv = *(const uint4*)&xb[((size_t)t1 * NB + b0 + xr_row) * DIN + xc]; }
  u64 hA0, hA1, hA2, hA3, hA4, hA5, hA6, hA7;
  u64 hB0, hB1, hB2, hB3, hB4, hB5, hB6, hB7;
  LOADH(1)
  __syncthreads();

  for (int s = 0; s < T_STEPS; ++s) {
    const int p = s & 1;
    const int t = d ? (1023 - s) : s;

    // park x(s+1) into the other buffer
    if (s < 1023) *(uint4*)&xsh[((p ^ 1) * 16 + xr_row) * 136 + xc] = xv;

    // x-part MFMA (LDS, no wait) while h A-frag loads stream in
    f32x4 acc0 = {bv, bv, bv, bv}, acc1 = {0.f, 0.f, 0.f, 0.f};
    {
      const u16* xr = &xsh[(p * 16 + (l & 15)) * 136 + (l >> 4) * 8];
      acc0 = MFMA(*(const short8*)(xr + 0),  Wx0, acc0, 0, 0, 0);
      acc1 = MFMA(*(const short8*)(xr + 32), Wx1, acc1, 0, 0, 0);
      acc0 = MFMA(*(const short8*)(xr + 64), Wx2, acc0, 0, 0, 0);
      acc1 = MFMA(*(const short8*)(xr + 96), Wx3, acc1, 0, 0, 0);
    }
    // h-part MFMA: A fragments straight from the in-flight agent loads
    acc0 = MFMA(MKA(hA0, hB0), Wh0, acc0, 0, 0, 0);
    acc1 = MFMA(MKA(hA1, hB1), Wh1, acc1, 0, 0, 0);
    acc0 = MFMA(MKA(hA2, hB2), Wh2, acc0, 0, 0, 0);
    acc1 = MFMA(MKA(hA3, hB3), Wh3, acc1, 0, 0, 0);
    acc0 = MFMA(MKA(hA4, hB4), Wh4, acc0, 0, 0, 0);
    acc1 = MFMA(MKA(hA5, hB5), Wh5, acc1, 0, 0, 0);
    acc0 = MFMA(MKA(hA6, hB6), Wh6, acc0, 0, 0, 0);
    acc1 = MFMA(MKA(hA7, hB7), Wh7, acc1, 0, 0, 0);
    acc0 = acc0 + acc1;

    // gates -> gl[m][n], n = local gate row
    {
      int n = w * 16 + (l & 15);
      int m0 = (l >> 4) * 4;
      gl[(m0 + 0) * 68 + n] = acc0[0]; gl[(m0 + 1) * 68 + n] = acc0[1];
      gl[(m0 + 2) * 68 + n] = acc0[2]; gl[(m0 + 3) * 68 + n] = acc0[3];
    }
    asm volatile("s_waitcnt lgkmcnt(0)" ::: "memory");
    __builtin_amdgcn_s_barrier();                // B2: gates published

    // elementwise (1 cell/thread, coalesced) + agent h-store
    float h, c;
    {
      f32x4 g4 = *(const f32x4*)&gl[eb * 68 + 4 * ej];
      float ii = sigm(g4[0]), ffg = sigm(g4[1]);
      float gg = tanh_fast(g4[2]), oo = sigm(g4[3]);
      c = ffg * c_reg + ii * gg;
      c_reg = c;
      h = oo * tanh_fast(c);
      __hip_atomic_store(hbuf + ((size_t)(p * 8 + grp) * 16 + eb) * 256 + jglob,
                         f2bf(h), __ATOMIC_RELAXED, __HIP_MEMORY_SCOPE_AGENT);
    }
    asm volatile("s_waitcnt vmcnt(0)" ::: "memory");   // h at LLC
    __builtin_amdgcn_s_barrier();                // B3: all h stores drained
    if (tid == 0 && s < 1023)
      __hip_atomic_store(flags + grp * WPG + jsl, (u32)(s + 1),
                         __ATOMIC_RELAXED, __HIP_MEMORY_SCOPE_AGENT);
    // fire-and-forget stores after the flag
    out[((size_t)t * NB + b0 + eb) * (2 * HID) + d * HID + jglob] = h;
    if (s == 1023) {
      out[TAIL_H + ((size_t)d * NB + b0 + eb) * HID + jglob] = h;
      out[TAIL_C + ((size_t)d * NB + b0 + eb) * HID + jglob] = c;
    }
    // x prefetch for s+2
    if (s < 1022) {
      int tn = d ? (1021 - s) : (s + 2);
      xv = *(const uint4*)&xb[((size_t)tn * NB + b0 + xr_row) * DIN + xc];
    }
    if (s < 1023) {
      if (tid == 0) {
        const u64* fl = (const u64*)(flags + grp * WPG);
        const u32 want = (u32)(s + 1);
        while (1) {
          u64 f0 = ALD64(fl + 0), f1 = ALD64(fl + 1), f2 = ALD64(fl + 2), f3 = ALD64(fl + 3);
          u64 f4 = ALD64(fl + 4), f5 = ALD64(fl + 5), f6 = ALD64(fl + 6), f7 = ALD64(fl + 7);
          u32 mn = 0xffffffffu;
          MN2(f0) MN2(f1) MN2(f2) MN2(f3) MN2(f4) MN2(f5) MN2(f6) MN2(f7)
          if (mn >= want) break;
          __builtin_amdgcn_s_sleep(1);
        }
      }
      __builtin_amdgcn_s_barrier();              // B4: group released
      // issue h(s) A-frag loads (parity p) -- consumed next iteration
      LOADH(p)
    }
  }
}

extern "C" void kernel_launch(void* const* d_in, const int* in_sizes, int n_in,
                              void* d_out, int out_size, void* d_ws, size_t ws_size,
                              hipStream_t stream) {
  const float* x     = (const float*)d_in[0];
  const float* hx    = (const float*)d_in[1];
  const float* cx    = (const float*)d_in[2];
  const float* Wih_f = (const float*)d_in[3];
  const float* Whh_f = (const float*)d_in[4];
  const float* bih_f = (const float*)d_in[5];
  const float* bhh_f = (const float*)d_in[6];
  const float* Wih_r = (const float*)d_in[7];
  const float* Whh_r = (const float*)d_in[8];
  const float* bih_r = (const float*)d_in[9];
  const float* bhh_r = (const float*)d_in[10];
  float* out = (float*)d_out;

  u16* Wg      = (u16*)((char*)d_ws + WG_OFF);
  float* bias4 = (float*)((char*)d_ws + BIAS_OFF);
  u16* xb      = (u16*)((char*)d_ws + XB_OFF);
  u16* hbuf    = (u16*)((char*)d_ws + HB_OFF);
  u32* flags   = (u32*)((char*)d_ws + FL_OFF);

  // Request 86,016 B dynamic LDS (uses ~13 KB): forces 1 WG/CU.
  hipFuncSetAttribute((const void*)lstm_r15,
                      hipFuncAttributeMaxDynamicSharedMemorySize, 86016);

  hipLaunchKernelGGL(prep_kernel, dim3(2048), dim3(256), 0, stream,
                     x, Wih_f, Whh_f, bih_f, bhh_f, Wih_r, Whh_r, bih_r, bhh_r,
                     hx, Wg, bias4, xb, hbuf, flags);
  hipLaunchKernelGGL(lstm_r15, dim3(128), dim3(256), 86016, stream,
                     Wg, bias4, xb, cx, hbuf, flags, out);
}

// Round 16
// 2313.758 us; speedup vs baseline: 1.6893x; 1.6893x over previous
//
#include <hip/hip_runtime.h>
#include <cstddef>

#define T_STEPS 1024
#define NB      64
#define DIN     128
#define HID     256
#define WPG     16

typedef unsigned short u16;
typedef unsigned int   u32;
typedef unsigned long long u64;
typedef __attribute__((ext_vector_type(8))) short short8;
typedef __attribute__((ext_vector_type(4))) float f32x4;

// ws byte offsets
#define WG_OFF   0u          // bf16 weights [2][1024 rows j*4+q][384 k] = 1,572,864 B
#define BIAS_OFF 1572864u    // f32 [2][1024]
#define XB_OFF   1581056u    // bf16 x [1024][64][128] = 16,777,216 B
#define HB_OFF   18358272u   // u16 hbuf [2 par][8 grp][16 b][256 j] = 131,072 B
#define FL_OFF   18489344u   // u32 flags [8 grp][16 wg] = 512 B

#define OUT_MAIN (T_STEPS * NB * 2 * HID)
#define TAIL_H   OUT_MAIN
#define TAIL_C   (OUT_MAIN + 2 * NB * HID)

__device__ __forceinline__ u16 f2bf(float f) {
  unsigned u = __float_as_uint(f);
  return (u16)((u + 0x7fffu + ((u >> 16) & 1u)) >> 16);  // RNE
}
__device__ __forceinline__ float sigm(float v) { return 1.f / (1.f + __expf(-v)); }
__device__ __forceinline__ float tanh_fast(float x) {
  float e = __expf(-2.f * fabsf(x));
  float r = (1.f - e) / (1.f + e);
  return x < 0.f ? -r : r;
}

__global__ void prep_kernel(const float* __restrict__ x,
                            const float* __restrict__ Wih_f, const float* __restrict__ Whh_f,
                            const float* __restrict__ bih_f, const float* __restrict__ bhh_f,
                            const float* __restrict__ Wih_r, const float* __restrict__ Whh_r,
                            const float* __restrict__ bih_r, const float* __restrict__ bhh_r,
                            const float* __restrict__ hx,
                            u16* __restrict__ Wg, float* __restrict__ bias4,
                            u16* __restrict__ xb, u16* __restrict__ hbuf,
                            u32* __restrict__ flags) {
  // segments: W 786432 | bias 2048 | xb 8388608 | hx-cells 32768 | flags 128
  const int total = 786432 + 2048 + 8388608 + 32768 + 128;
  for (int i = blockIdx.x * blockDim.x + threadIdx.x; i < total;
       i += gridDim.x * blockDim.x) {
    if (i < 786432) {
      int d = i / 393216;
      int r = i - d * 393216;
      int rowg = r / 384, k = r - rowg * 384;   // rowg = j*4+q interleaved
      int j = rowg >> 2, q = rowg & 3;
      int g = q * HID + j;                      // torch gate row
      const float* Wih = d ? Wih_r : Wih_f;
      const float* Whh = d ? Whh_r : Whh_f;
      float v = (k < DIN) ? Wih[g * DIN + k] : Whh[g * HID + (k - DIN)];
      Wg[i] = f2bf(v);
    } else if (i < 786432 + 2048) {
      int r = i - 786432;
      int d = r >> 10, rowg = r & 1023;
      int j = rowg >> 2, q = rowg & 3;
      int g = q * HID + j;
      bias4[r] = d ? (bih_r[g] + bhh_r[g]) : (bih_f[g] + bhh_f[g]);
    } else if (i < 786432 + 2048 + 8388608) {
      int r = i - (786432 + 2048);
      xb[r] = f2bf(x[r]);                       // [t][b][k]
    } else if (i < 786432 + 2048 + 8388608 + 32768) {
      int r = i - (786432 + 2048 + 8388608);    // (d*64+b)*256 + j
      int d = r >> 14, b = (r >> 8) & 63, j = r & 255;
      int grp = d * 4 + (b >> 4), bb = b & 15;
      hbuf[((size_t)(8 + grp) * 16 + bb) * 256 + j] = f2bf(hx[r]);  // parity 1
      hbuf[((size_t)(0 + grp) * 16 + bb) * 256 + j] = 0;            // parity 0
    } else {
      flags[i - (786432 + 2048 + 8388608 + 32768)] = 0u;
    }
  }
}

#define MFMA __builtin_amdgcn_mfma_f32_16x16x32_bf16
#define ALD64(P) __hip_atomic_load((P), __ATOMIC_RELAXED, __HIP_MEMORY_SCOPE_AGENT)
#define MN2(F) { u32 a_ = (u32)(F), b_ = (u32)((F) >> 32); \
                 mn = mn < a_ ? mn : a_; mn = mn < b_ ? mn : b_; }

// 128 WGs x 256 thr. grp = bid&7 = d*4+btile (16 WGs/group), jsl = bid>>3.
// Per WG: 64 gate rows, 16 batches. r9 skeleton (coalesced h transport + LDS
// park + B1..B4 ordering) with: (1) weights in 12 named VGPR fragments,
// (2) per-producer value flags (no RMW), (3) x-MFMA of step s+1 hoisted
// before the poll so only {h-load, park, h-MFMA, EW} sit post-release.
__global__ __launch_bounds__(256, 1) void lstm_r16(
    const u16* __restrict__ Wg, const float* __restrict__ bias4,
    const u16* __restrict__ xb, const float* __restrict__ cx,
    u16* __restrict__ hbuf, u32* __restrict__ flags,
    float* __restrict__ out) {
  extern __shared__ char smem[];
  u16* xsh  = (u16*)smem;                 // [2][16][136]  8,704 B
  u16* hsh  = (u16*)(smem + 8704);        // [16][264]     8,448 B
  float* gl = (float*)(smem + 17152);     // [16 m][68 n]  4,352 B (tot 21,504)

  const int tid = threadIdx.x;
  const int bid = blockIdx.x;
  const int grp = bid & 7;
  const int jsl = bid >> 3;
  const int d = grp >> 2, b0 = (grp & 3) * 16;
  const int w = tid >> 6, l = tid & 63;

  // one-time: 12 weight fragments -> named VGPRs (r13-proven codegen)
  const u16* wgb = Wg + ((size_t)(d * 1024 + jsl * 64 + w * 16 + (l & 15))) * 384
                      + (l >> 4) * 8;
  short8 Wx0 = *(const short8*)(wgb + 0);
  short8 Wx1 = *(const short8*)(wgb + 32);
  short8 Wx2 = *(const short8*)(wgb + 64);
  short8 Wx3 = *(const short8*)(wgb + 96);
  short8 Wh0 = *(const short8*)(wgb + 128);
  short8 Wh1 = *(const short8*)(wgb + 160);
  short8 Wh2 = *(const short8*)(wgb + 192);
  short8 Wh3 = *(const short8*)(wgb + 224);
  short8 Wh4 = *(const short8*)(wgb + 256);
  short8 Wh5 = *(const short8*)(wgb + 288);
  short8 Wh6 = *(const short8*)(wgb + 320);
  short8 Wh7 = *(const short8*)(wgb + 352);
  const float bv = bias4[d * 1024 + jsl * 64 + w * 16 + (l & 15)];

  // elementwise identity (r9 coalesced): eb = batch, ej = j slot
  const int eb = tid >> 4, ej = tid & 15;
  const int jglob = jsl * 16 + ej;
  float c_reg = cx[((size_t)d * NB + b0 + eb) * HID + jglob];

  const int xr_row = tid >> 4;            // x stage row (16 batches)
  const int xc = (tid & 15) * 8;          // 8 u16 = 16 B per thread
  const int pb = tid >> 4;                // h consumer batch
  const int cj0 = (tid & 15) * 16;        // 16 h cells per thread

  // prologue: park x(t0), prefetch x(t1), issue h(init) loads (parity 1)
  { int t0 = d ? 1023 : 0;
    *(uint4*)&xsh[(0 * 16 + xr_row) * 136 + xc] =
        *(const uint4*)&xb[((size_t)t0 * NB + b0 + xr_row) * DIN + xc]; }
  uint4 xv;
  { int t1 = d ? 1022 : 1;
    xv = *(const uint4*)&xb[((size_t)t1 * NB + b0 + xr_row) * DIN + xc]; }
  u64 h0, h1, h2, h3;
  { const u64* hp = (const u64*)(hbuf + ((size_t)(8 + grp) * 16 + pb) * 256 + cj0);
    h0 = ALD64(hp + 0); h1 = ALD64(hp + 1); h2 = ALD64(hp + 2); h3 = ALD64(hp + 3); }
  __syncthreads();

  // prologue x-MFMA for step 0 (reads xsh parity 0)
  f32x4 acc0 = {bv, bv, bv, bv}, acc1 = {0.f, 0.f, 0.f, 0.f};
  {
    const u16* xr = &xsh[(0 * 16 + (l & 15)) * 136 + (l >> 4) * 8];
    acc0 = MFMA(*(const short8*)(xr + 0),  Wx0, acc0, 0, 0, 0);
    acc1 = MFMA(*(const short8*)(xr + 32), Wx1, acc1, 0, 0, 0);
    acc0 = MFMA(*(const short8*)(xr + 64), Wx2, acc0, 0, 0, 0);
    acc1 = MFMA(*(const short8*)(xr + 96), Wx3, acc1, 0, 0, 0);
  }

  for (int s = 0; s < T_STEPS; ++s) {
    const int p = s & 1;
    const int t = d ? (1023 - s) : s;

    // 1. park h(s-1) (waits vmcnt on h regs only)
    {
      uint4 H0, H1;
      H0.x = (u32)h0; H0.y = (u32)(h0 >> 32); H0.z = (u32)h1; H0.w = (u32)(h1 >> 32);
      H1.x = (u32)h2; H1.y = (u32)(h2 >> 32); H1.z = (u32)h3; H1.w = (u32)(h3 >> 32);
      *(uint4*)&hsh[pb * 264 + cj0] = H0;
      *(uint4*)&hsh[pb * 264 + cj0 + 8] = H1;
    }
    asm volatile("s_waitcnt lgkmcnt(0)" ::: "memory");
    __builtin_amdgcn_s_barrier();                // B1: h parked

    // 2. h-part MFMA (weights from VGPRs; acc pre-seeded with bias + x part)
    {
      const u16* hr = &hsh[(l & 15) * 264 + (l >> 4) * 8];
      acc0 = MFMA(*(const short8*)(hr + 0),   Wh0, acc0, 0, 0, 0);
      acc1 = MFMA(*(const short8*)(hr + 32),  Wh1, acc1, 0, 0, 0);
      acc0 = MFMA(*(const short8*)(hr + 64),  Wh2, acc0, 0, 0, 0);
      acc1 = MFMA(*(const short8*)(hr + 96),  Wh3, acc1, 0, 0, 0);
      acc0 = MFMA(*(const short8*)(hr + 128), Wh4, acc0, 0, 0, 0);
      acc1 = MFMA(*(const short8*)(hr + 160), Wh5, acc1, 0, 0, 0);
      acc0 = MFMA(*(const short8*)(hr + 192), Wh6, acc0, 0, 0, 0);
      acc1 = MFMA(*(const short8*)(hr + 224), Wh7, acc1, 0, 0, 0);
    }
    acc0 = acc0 + acc1;

    // 3. gates -> gl[m][n]
    {
      int n = w * 16 + (l & 15);
      int m0 = (l >> 4) * 4;
      gl[(m0 + 0) * 68 + n] = acc0[0]; gl[(m0 + 1) * 68 + n] = acc0[1];
      gl[(m0 + 2) * 68 + n] = acc0[2]; gl[(m0 + 3) * 68 + n] = acc0[3];
    }
    asm volatile("s_waitcnt lgkmcnt(0)" ::: "memory");
    __builtin_amdgcn_s_barrier();                // B2: gates published

    // 4. elementwise (1 cell/thread, coalesced) + agent h-store
    float h, c;
    {
      f32x4 g4 = *(const f32x4*)&gl[eb * 68 + 4 * ej];
      float ii = sigm(g4[0]), ffg = sigm(g4[1]);
      float gg = tanh_fast(g4[2]), oo = sigm(g4[3]);
      c = ffg * c_reg + ii * gg;
      c_reg = c;
      h = oo * tanh_fast(c);
      __hip_atomic_store(hbuf + ((size_t)(p * 8 + grp) * 16 + eb) * 256 + jglob,
                         f2bf(h), __ATOMIC_RELAXED, __HIP_MEMORY_SCOPE_AGENT);
    }
    // 5. park x(s+1) pre-drain (LDS; B3 will order it for step 10's read)
    if (s < 1023) *(uint4*)&xsh[((p ^ 1) * 16 + xr_row) * 136 + xc] = xv;
    // 6. drain h stores (xv(s+2) not yet issued) + LDS ordering + B3
    asm volatile("s_waitcnt vmcnt(0) lgkmcnt(0)" ::: "memory");
    __builtin_amdgcn_s_barrier();                // B3: h at LLC, x parked
    // 7. per-producer value flag (plain store, no RMW)
    if (tid == 0 && s < 1023)
      __hip_atomic_store(flags + grp * WPG + jsl, (u32)(s + 1),
                         __ATOMIC_RELAXED, __HIP_MEMORY_SCOPE_AGENT);
    // 8. fire-and-forget out stores (after flag)
    out[((size_t)t * NB + b0 + eb) * (2 * HID) + d * HID + jglob] = h;
    if (s == 1023) {
      out[TAIL_H + ((size_t)d * NB + b0 + eb) * HID + jglob] = h;
      out[TAIL_C + ((size_t)d * NB + b0 + eb) * HID + jglob] = c;
    }
    // 9. x global prefetch for s+2
    if (s < 1022) {
      int tn = d ? (1021 - s) : (s + 2);
      xv = *(const uint4*)&xb[((size_t)tn * NB + b0 + xr_row) * DIN + xc];
    }
    if (s < 1023) {
      // 10. x-part MFMA for step s+1 (reads xsh[p^1]; overlaps the poll)
      acc0[0] = bv; acc0[1] = bv; acc0[2] = bv; acc0[3] = bv;
      acc1[0] = 0.f; acc1[1] = 0.f; acc1[2] = 0.f; acc1[3] = 0.f;
      {
        const u16* xr = &xsh[((p ^ 1) * 16 + (l & 15)) * 136 + (l >> 4) * 8];
        acc0 = MFMA(*(const short8*)(xr + 0),  Wx0, acc0, 0, 0, 0);
        acc1 = MFMA(*(const short8*)(xr + 32), Wx1, acc1, 0, 0, 0);
        acc0 = MFMA(*(const short8*)(xr + 64), Wx2, acc0, 0, 0, 0);
        acc1 = MFMA(*(const short8*)(xr + 96), Wx3, acc1, 0, 0, 0);
      }
      // 11. tid0 polls the 16-flag line (8 parallel u64 loads, no sleep)
      if (tid == 0) {
        const u64* fl = (const u64*)(flags + grp * WPG);
        const u32 want = (u32)(s + 1);
        while (1) {
          u64 f0 = ALD64(fl + 0), f1 = ALD64(fl + 1), f2 = ALD64(fl + 2), f3 = ALD64(fl + 3);
          u64 f4 = ALD64(fl + 4), f5 = ALD64(fl + 5), f6 = ALD64(fl + 6), f7 = ALD64(fl + 7);
          u32 mn = 0xffffffffu;
          MN2(f0) MN2(f1) MN2(f2) MN2(f3) MN2(f4) MN2(f5) MN2(f6) MN2(f7)
          if (mn >= want) break;
        }
      }
      __builtin_amdgcn_s_barrier();              // B4: group released
      // 12. issue h(s) loads (parity p, coalesced) -- parked next iteration
      const u64* hp = (const u64*)(hbuf + ((size_t)(p * 8 + grp) * 16 + pb) * 256 + cj0);
      h0 = ALD64(hp + 0); h1 = ALD64(hp + 1); h2 = ALD64(hp + 2); h3 = ALD64(hp + 3);
    }
  }
}

extern "C" void kernel_launch(void* const* d_in, const int* in_sizes, int n_in,
                              void* d_out, int out_size, void* d_ws, size_t ws_size,
                              hipStream_t stream) {
  const float* x     = (const float*)d_in[0];
  const float* hx    = (const float*)d_in[1];
  const float* cx    = (const float*)d_in[2];
  const float* Wih_f = (const float*)d_in[3];
  const float* Whh_f = (const float*)d_in[4];
  const float* bih_f = (const float*)d_in[5];
  const float* bhh_f = (const float*)d_in[6];
  const float* Wih_r = (const float*)d_in[7];
  const float* Whh_r = (const float*)d_in[8];
  const float* bih_r = (const float*)d_in[9];
  const float* bhh_r = (const float*)d_in[10];
  float* out = (float*)d_out;

  u16* Wg      = (u16*)((char*)d_ws + WG_OFF);
  float* bias4 = (float*)((char*)d_ws + BIAS_OFF);
  u16* xb      = (u16*)((char*)d_ws + XB_OFF);
  u16* hbuf    = (u16*)((char*)d_ws + HB_OFF);
  u32* flags   = (u32*)((char*)d_ws + FL_OFF);

  // Request 86,016 B dynamic LDS (uses ~21.5 KB): forces 1 WG/CU.
  hipFuncSetAttribute((const void*)lstm_r16,
                      hipFuncAttributeMaxDynamicSharedMemorySize, 86016);

  hipLaunchKernelGGL(prep_kernel, dim3(2048), dim3(256), 0, stream,
                     x, Wih_f, Whh_f, bih_f, bhh_f, Wih_r, Whh_r, bih_r, bhh_r,
                     hx, Wg, bias4, xb, hbuf, flags);
  hipLaunchKernelGGL(lstm_r16, dim3(128), dim3(256), 86016, stream,
                     Wg, bias4, xb, cx, hbuf, flags, out);
}

// Round 17
// 2049.503 us; speedup vs baseline: 1.9071x; 1.1289x over previous
//
#include <hip/hip_runtime.h>
#include <cstddef>

#define T_STEPS 1024
#define NB      64
#define DIN     128
#define HID     256
#define WPG     16

typedef unsigned short u16;
typedef unsigned int   u32;
typedef unsigned long long u64;
typedef __attribute__((ext_vector_type(8))) short short8;
typedef __attribute__((ext_vector_type(4))) float f32x4;

// ws byte offsets
#define WG_OFF   0u          // bf16 weights [2][1024 rows j*4+q][384 k] = 1,572,864 B
#define BIAS_OFF 1572864u    // f32 [2][1024]
#define XB_OFF   1581056u    // bf16 x [1024][64][128] = 16,777,216 B
#define HB_OFF   18358272u   // u16 hbuf [2 par][8 grp][16 b][256 j] = 131,072 B
#define FL_OFF   18489344u   // u32 flags [8 grp][1024 steps] = 32,768 B

#define OUT_MAIN (T_STEPS * NB * 2 * HID)
#define TAIL_H   OUT_MAIN
#define TAIL_C   (OUT_MAIN + 2 * NB * HID)

__device__ __forceinline__ u16 f2bf(float f) {
  unsigned u = __float_as_uint(f);
  return (u16)((u + 0x7fffu + ((u >> 16) & 1u)) >> 16);  // RNE
}
__device__ __forceinline__ float sigm(float v) { return 1.f / (1.f + __expf(-v)); }
__device__ __forceinline__ float tanh_fast(float x) {
  float e = __expf(-2.f * fabsf(x));
  float r = (1.f - e) / (1.f + e);
  return x < 0.f ? -r : r;
}

__global__ void prep_kernel(const float* __restrict__ x,
                            const float* __restrict__ Wih_f, const float* __restrict__ Whh_f,
                            const float* __restrict__ bih_f, const float* __restrict__ bhh_f,
                            const float* __restrict__ Wih_r, const float* __restrict__ Whh_r,
                            const float* __restrict__ bih_r, const float* __restrict__ bhh_r,
                            const float* __restrict__ hx,
                            u16* __restrict__ Wg, float* __restrict__ bias4,
                            u16* __restrict__ xb, u16* __restrict__ hbuf,
                            u32* __restrict__ flags) {
  // segments: W 786432 | bias 2048 | xb 8388608 | hx-cells 32768 | flags 8192
  const int total = 786432 + 2048 + 8388608 + 32768 + 8192;
  for (int i = blockIdx.x * blockDim.x + threadIdx.x; i < total;
       i += gridDim.x * blockDim.x) {
    if (i < 786432) {
      int d = i / 393216;
      int r = i - d * 393216;
      int rowg = r / 384, k = r - rowg * 384;   // rowg = j*4+q interleaved
      int j = rowg >> 2, q = rowg & 3;
      int g = q * HID + j;                      // torch gate row
      const float* Wih = d ? Wih_r : Wih_f;
      const float* Whh = d ? Whh_r : Whh_f;
      float v = (k < DIN) ? Wih[g * DIN + k] : Whh[g * HID + (k - DIN)];
      Wg[i] = f2bf(v);
    } else if (i < 786432 + 2048) {
      int r = i - 786432;
      int d = r >> 10, rowg = r & 1023;
      int j = rowg >> 2, q = rowg & 3;
      int g = q * HID + j;
      bias4[r] = d ? (bih_r[g] + bhh_r[g]) : (bih_f[g] + bhh_f[g]);
    } else if (i < 786432 + 2048 + 8388608) {
      int r = i - (786432 + 2048);
      xb[r] = f2bf(x[r]);                       // [t][b][k]
    } else if (i < 786432 + 2048 + 8388608 + 32768) {
      int r = i - (786432 + 2048 + 8388608);    // (d*64+b)*256 + j
      int d = r >> 14, b = (r >> 8) & 63, j = r & 255;
      int grp = d * 4 + (b >> 4), bb = b & 15;
      hbuf[((size_t)(8 + grp) * 16 + bb) * 256 + j] = f2bf(hx[r]);  // parity 1
      hbuf[((size_t)(0 + grp) * 16 + bb) * 256 + j] = 0;            // parity 0
    } else {
      int r = i - (786432 + 2048 + 8388608 + 32768);  // g*1024 + s
      flags[r] = ((r & 1023) == 0) ? (u32)WPG : 0u;   // step 0 pre-released
    }
  }
}

#define MFMA __builtin_amdgcn_mfma_f32_16x16x32_bf16
#define ALD64(P) __hip_atomic_load((P), __ATOMIC_RELAXED, __HIP_MEMORY_SCOPE_AGENT)

// 128 WGs x 256 thr. grp = bid&7 (co-XCD under round-robin), jsl = bid>>3.
// grp = d*4 + btile: 8 groups x 16 WGs. Per WG: 64 gate rows, 16 batches.
// r9's exact protocol (fetch_add release, tid0 sleep-poll, B1..B4); ONLY
// change vs r9: weights live in 12 named VGPR fragments instead of LDS.
__global__ __launch_bounds__(256, 1) void lstm_r17(
    const u16* __restrict__ Wg, const float* __restrict__ bias4,
    const u16* __restrict__ xb, const float* __restrict__ cx,
    u16* __restrict__ hbuf, u32* __restrict__ flags,
    float* __restrict__ out) {
  extern __shared__ char smem[];
  u16* xsh  = (u16*)smem;                 // [2][16][136]  8,704 B
  u16* hsh  = (u16*)(smem + 8704);        // [16][264]     8,448 B
  float* gl = (float*)(smem + 17152);     // [16][68]      4,352 B  (tot 21,504)

  const int tid = threadIdx.x;
  const int bid = blockIdx.x;
  const int grp = bid & 7;
  const int jsl = bid >> 3;
  const int d = grp >> 2, b0 = (grp & 3) * 16;
  const int w = tid >> 6, l = tid & 63;

  // one-time: 12 weight fragments -> named VGPRs (r13-proven codegen, no spill)
  const u16* wgb = Wg + ((size_t)(d * 1024 + jsl * 64 + w * 16 + (l & 15))) * 384
                      + (l >> 4) * 8;
  short8 Wx0 = *(const short8*)(wgb + 0);
  short8 Wx1 = *(const short8*)(wgb + 32);
  short8 Wx2 = *(const short8*)(wgb + 64);
  short8 Wx3 = *(const short8*)(wgb + 96);
  short8 Wh0 = *(const short8*)(wgb + 128);
  short8 Wh1 = *(const short8*)(wgb + 160);
  short8 Wh2 = *(const short8*)(wgb + 192);
  short8 Wh3 = *(const short8*)(wgb + 224);
  short8 Wh4 = *(const short8*)(wgb + 256);
  short8 Wh5 = *(const short8*)(wgb + 288);
  short8 Wh6 = *(const short8*)(wgb + 320);
  short8 Wh7 = *(const short8*)(wgb + 352);
  const float bv = bias4[d * 1024 + jsl * 64 + w * 16 + (l & 15)];

  // elementwise identity: 1 cell/thread: eb = batch, ej = local j
  const int eb = tid >> 4, ej = tid & 15;
  const int jglob = jsl * 16 + ej;
  float c_reg = cx[((size_t)d * NB + b0 + eb) * HID + jglob];

  const int xr_row = tid >> 4;            // x stage row (16 batches)
  const int xc = (tid & 15) * 8;          // 8 u16 = 16 B per thread
  const int pb = tid >> 4;                // h consumer batch
  const int cj0 = (tid & 15) * 16;        // 16 h cells per thread

  // prologue: stage x(t0), prefetch x(t1), issue h(init) loads (parity 1)
  { int t0 = d ? 1023 : 0;
    *(uint4*)&xsh[(0 * 16 + xr_row) * 136 + xc] =
        *(const uint4*)&xb[((size_t)t0 * NB + b0 + xr_row) * DIN + xc]; }
  uint4 xv;
  { int t1 = d ? 1022 : 1;
    xv = *(const uint4*)&xb[((size_t)t1 * NB + b0 + xr_row) * DIN + xc]; }
  u64 h0, h1, h2, h3;
  { const u64* hp = (const u64*)(hbuf + ((size_t)(8 + grp) * 16 + pb) * 256 + cj0);
    h0 = ALD64(hp + 0); h1 = ALD64(hp + 1); h2 = ALD64(hp + 2); h3 = ALD64(hp + 3); }
  __syncthreads();

  for (int s = 0; s < T_STEPS; ++s) {
    const int p = s & 1;
    const int t = d ? (1023 - s) : s;

    // park x(s+1) into the other buffer
    if (s < 1023) *(uint4*)&xsh[((p ^ 1) * 16 + xr_row) * 136 + xc] = xv;

    // x-part MFMA (hides in-flight h loads); weights from VGPRs
    f32x4 acc = {bv, bv, bv, bv};
    {
      const u16* xr = &xsh[(p * 16 + (l & 15)) * 136 + (l >> 4) * 8];
      acc = MFMA(*(const short8*)(xr + 0),  Wx0, acc, 0, 0, 0);
      acc = MFMA(*(const short8*)(xr + 32), Wx1, acc, 0, 0, 0);
      acc = MFMA(*(const short8*)(xr + 64), Wx2, acc, 0, 0, 0);
      acc = MFMA(*(const short8*)(xr + 96), Wx3, acc, 0, 0, 0);
    }
    // park h (waits vmcnt on h regs only)
    {
      uint4 H0, H1;
      H0.x = (u32)h0; H0.y = (u32)(h0 >> 32); H0.z = (u32)h1; H0.w = (u32)(h1 >> 32);
      H1.x = (u32)h2; H1.y = (u32)(h2 >> 32); H1.z = (u32)h3; H1.w = (u32)(h3 >> 32);
      *(uint4*)&hsh[pb * 264 + cj0] = H0;
      *(uint4*)&hsh[pb * 264 + cj0 + 8] = H1;
    }
    asm volatile("s_waitcnt lgkmcnt(0)" ::: "memory");
    __builtin_amdgcn_s_barrier();                // B1: h parked

    // h-part MFMA: weights from registers, h fragments from LDS
    {
      const u16* hr = &hsh[(l & 15) * 264 + (l >> 4) * 8];
      acc = MFMA(*(const short8*)(hr + 0),   Wh0, acc, 0, 0, 0);
      acc = MFMA(*(const short8*)(hr + 32),  Wh1, acc, 0, 0, 0);
      acc = MFMA(*(const short8*)(hr + 64),  Wh2, acc, 0, 0, 0);
      acc = MFMA(*(const short8*)(hr + 96),  Wh3, acc, 0, 0, 0);
      acc = MFMA(*(const short8*)(hr + 128), Wh4, acc, 0, 0, 0);
      acc = MFMA(*(const short8*)(hr + 160), Wh5, acc, 0, 0, 0);
      acc = MFMA(*(const short8*)(hr + 192), Wh6, acc, 0, 0, 0);
      acc = MFMA(*(const short8*)(hr + 224), Wh7, acc, 0, 0, 0);
    }
    {
      int n = w * 16 + (l & 15);
      int m0 = (l >> 4) * 4;
      gl[(m0 + 0) * 68 + n] = acc[0]; gl[(m0 + 1) * 68 + n] = acc[1];
      gl[(m0 + 2) * 68 + n] = acc[2]; gl[(m0 + 3) * 68 + n] = acc[3];
    }
    asm volatile("s_waitcnt lgkmcnt(0)" ::: "memory");
    __builtin_amdgcn_s_barrier();                // B2: gates published

    // elementwise (all 256 threads) + agent h-store
    f32x4 g4 = *(const f32x4*)&gl[eb * 68 + 4 * ej];
    float ii = sigm(g4[0]), ff = sigm(g4[1]);
    float gg = tanh_fast(g4[2]), oo = sigm(g4[3]);
    float c = ff * c_reg + ii * gg;
    c_reg = c;
    float h = oo * tanh_fast(c);
    u16 hb16 = f2bf(h);
    __hip_atomic_store(hbuf + ((size_t)(p * 8 + grp) * 16 + eb) * 256 + jglob,
                       hb16, __ATOMIC_RELAXED, __HIP_MEMORY_SCOPE_AGENT);
    asm volatile("s_waitcnt vmcnt(0)" ::: "memory");   // h at LLC
    __builtin_amdgcn_s_barrier();                // B3: all h stores drained
    if (tid == 0 && s < 1023)
      __hip_atomic_fetch_add(flags + grp * 1024 + (s + 1), 1u,
                             __ATOMIC_RELAXED, __HIP_MEMORY_SCOPE_AGENT);
    // fire-and-forget stores after the flag
    out[((size_t)t * NB + b0 + eb) * (2 * HID) + d * HID + jglob] = h;
    if (s == 1023) {
      out[TAIL_H + ((size_t)d * NB + b0 + eb) * HID + jglob] = h;
      out[TAIL_C + ((size_t)d * NB + b0 + eb) * HID + jglob] = c;
    }
    // x prefetch for s+2
    if (s < 1022) {
      int tn = d ? (1021 - s) : (s + 2);
      xv = *(const uint4*)&xb[((size_t)tn * NB + b0 + xr_row) * DIN + xc];
    }
    if (s < 1023) {
      if (tid == 0) {
        const u32* fp = flags + grp * 1024 + (s + 1);
        while (__hip_atomic_load(fp, __ATOMIC_RELAXED, __HIP_MEMORY_SCOPE_AGENT) < WPG)
          __builtin_amdgcn_s_sleep(1);
      }
      __builtin_amdgcn_s_barrier();              // B4: group released
      // issue h(s) loads (parity p) -- hidden under next step's x-GEMM
      const u64* hp = (const u64*)(hbuf + ((size_t)(p * 8 + grp) * 16 + pb) * 256 + cj0);
      h0 = ALD64(hp + 0); h1 = ALD64(hp + 1); h2 = ALD64(hp + 2); h3 = ALD64(hp + 3);
    }
  }
}

extern "C" void kernel_launch(void* const* d_in, const int* in_sizes, int n_in,
                              void* d_out, int out_size, void* d_ws, size_t ws_size,
                              hipStream_t stream) {
  const float* x     = (const float*)d_in[0];
  const float* hx    = (const float*)d_in[1];
  const float* cx    = (const float*)d_in[2];
  const float* Wih_f = (const float*)d_in[3];
  const float* Whh_f = (const float*)d_in[4];
  const float* bih_f = (const float*)d_in[5];
  const float* bhh_f = (const float*)d_in[6];
  const float* Wih_r = (const float*)d_in[7];
  const float* Whh_r = (const float*)d_in[8];
  const float* bih_r = (const float*)d_in[9];
  const float* bhh_r = (const float*)d_in[10];
  float* out = (float*)d_out;

  u16* Wg      = (u16*)((char*)d_ws + WG_OFF);
  float* bias4 = (float*)((char*)d_ws + BIAS_OFF);
  u16* xb      = (u16*)((char*)d_ws + XB_OFF);
  u16* hbuf    = (u16*)((char*)d_ws + HB_OFF);
  u32* flags   = (u32*)((char*)d_ws + FL_OFF);

  // Request 86,016 B dynamic LDS (uses ~21.5 KB): forces 1 WG/CU.
  hipFuncSetAttribute((const void*)lstm_r17,
                      hipFuncAttributeMaxDynamicSharedMemorySize, 86016);

  hipLaunchKernelGGL(prep_kernel, dim3(2048), dim3(256), 0, stream,
                     x, Wih_f, Whh_f, bih_f, bhh_f, Wih_r, Whh_r, bih_r, bhh_r,
                     hx, Wg, bias4, xb, hbuf, flags);
  hipLaunchKernelGGL(lstm_r17, dim3(128), dim3(256), 86016, stream,
                     Wg, bias4, xb, cx, hbuf, flags, out);
}